// Round 11
// baseline (410.007 us; speedup 1.0000x reference)
//
#include <hip/hip_runtime.h>
#include <stdint.h>

typedef uint16_t u16;
typedef __attribute__((ext_vector_type(8))) short bf16x8;
typedef __attribute__((ext_vector_type(4))) float f32x4;

__device__ inline u16 f2b(float f) {          // fp32 -> bf16 RNE
  uint32_t u = __float_as_uint(f);
  u += 0x7FFF + ((u >> 16) & 1);
  return (u16)(u >> 16);
}
__device__ inline float b2f(u16 h) {          // bf16 -> fp32 exact
  return __uint_as_float(((uint32_t)h) << 16);
}

// Async global->LDS DMA, 16B per lane.
typedef __attribute__((address_space(1))) void gvoid;
typedef __attribute__((address_space(3))) void lvoid;
#define GLOAD16(gp, lp)                                                        \
  __builtin_amdgcn_global_load_lds((gvoid*)(gp), (lvoid*)(lp), 16, 0, 0)

// ---------------------------------------------------------------------------
// Inline dtype probe: mode 0 = bf16, 1 = fp32 (R4-proven).
// ---------------------------------------------------------------------------
__device__ __forceinline__ int probe_mode(const u16* __restrict__ P, int t,
                                          int* cnt_sh) {
  if (t == 0) *cnt_sh = 0;
  __syncthreads();
  float av = fabsf(b2f(P[t * 2]));
  if (av >= 1000.0f) atomicAdd(cnt_sh, 1);
  __syncthreads();
  return (*cnt_sh > 16) ? 1 : 0;
}

// ---------------------------------------------------------------------------
// Kernel 1: qkv = x @ w_qkv^T + RoPE/V-transpose. THIS ROUND: ported onto
// the R9-gemm_out PROVEN staging template — BK 32 -> 64 (16 K-steps, halves
// the fixed per-step barrier/drain cost), global_load_lds staging into
// [64][64] tiles with granule-XOR swizzle on BOTH sides (rule #21; 2-way =
// free per m136), double-buffered, ONE barrier per step. Same fused
// (2 m-half x 3 e) structure and T1 XCD remap as R9. Cs unioned (80 KB,
// 2 blocks/CU unchanged).
// ---------------------------------------------------------------------------
__global__ __launch_bounds__(256) void k_qkv_rope(const void* __restrict__ Xv,
                                                  const void* __restrict__ Wv,
                                                  u16* __restrict__ Qo,
                                                  u16* __restrict__ Ko,
                                                  u16* __restrict__ Vo) {
  union ShQ {
    struct { u16 A[2][2][64][64]; u16 B[2][3][64][64]; } st;  // 80 KB
    float Cs[64][66];
  };
  __shared__ ShQ sh;
  __shared__ int cnt_sh;
  const int t = threadIdx.x, w = t >> 6, lane = t & 63;
  const int mode = probe_mode((const u16*)Xv, t, &cnt_sh);
  // T1 XCD swizzle (R8-proven): id in [0,512), xcd = id&7, p = id>>3;
  // h = p>>2 (outer), m-tile = xcd*4 + (p&3) (inner). Bijective (512%8==0).
  const int id = blockIdx.y * 16 + blockIdx.x;
  const int xcd = id & 7, p = id >> 3;
  const int h = p >> 2;                   // head 0..15
  const int n0h = h * 64;
  const int m0 = ((xcd << 2) | (p & 3)) << 7;   // m-tile*128
  const int lr = lane & 15, lq = lane >> 4;
  f32x4 acc[3][2][4] = {};                // [e][m-half][mt]

  if (mode == 0) {
    const u16* Xp = (const u16*)Xv;
    const u16* Wp = (const u16*)Wv;
    // staging geometry (R9-gemm-verbatim): row = 64 u16 = 8 granules of 16B.
    // gload_lds lane l -> row base+(l>>3), phys granule l&7; source granule
    // pre-swizzled (l&7)^(l>>3) == (row&7). Wave w stages rows [w*8,w*8+8)
    // and [w*8+32,w*8+40) of each 64-row tile.
    const int lrow = lane >> 3;           // 0..7
    const int lg   = (lane & 7) ^ lrow;   // pre-swizzled source granule
    const long a0r0 = (long)(m0 + w * 8 + lrow) * 1024 + lg * 8;
    const long a0r1 = (long)(m0 + w * 8 + 32 + lrow) * 1024 + lg * 8;
    const long a1r0 = (long)(m0 + 64 + w * 8 + lrow) * 1024 + lg * 8;
    const long a1r1 = (long)(m0 + 64 + w * 8 + 32 + lrow) * 1024 + lg * 8;
    const long b_r0 = (long)(n0h + w * 8 + lrow) * 1024 + lg * 8;
    const long b_r1 = (long)(n0h + w * 8 + 32 + lrow) * 1024 + lg * 8;
#define STAGE_QKV(buf, kk)                                                     \
    do {                                                                       \
      GLOAD16(Xp + a0r0 + (kk),           &sh.st.A[buf][0][w * 8][0]);         \
      GLOAD16(Xp + a0r1 + (kk),           &sh.st.A[buf][0][w * 8 + 32][0]);    \
      GLOAD16(Xp + a1r0 + (kk),           &sh.st.A[buf][1][w * 8][0]);         \
      GLOAD16(Xp + a1r1 + (kk),           &sh.st.A[buf][1][w * 8 + 32][0]);    \
      GLOAD16(Wp + b_r0 + (kk),           &sh.st.B[buf][0][w * 8][0]);         \
      GLOAD16(Wp + b_r1 + (kk),           &sh.st.B[buf][0][w * 8 + 32][0]);    \
      GLOAD16(Wp + b_r0 + 1048576 + (kk), &sh.st.B[buf][1][w * 8][0]);         \
      GLOAD16(Wp + b_r1 + 1048576 + (kk), &sh.st.B[buf][1][w * 8 + 32][0]);    \
      GLOAD16(Wp + b_r0 + 2097152 + (kk), &sh.st.B[buf][2][w * 8][0]);         \
      GLOAD16(Wp + b_r1 + 2097152 + (kk), &sh.st.B[buf][2][w * 8 + 32][0]);    \
    } while (0)
    STAGE_QKV(0, 0);
    asm volatile("s_waitcnt vmcnt(0)" ::: "memory");
    __syncthreads();
    int cur = 0;
    for (int k0 = 0; k0 < 1024; k0 += 64) {
      if (k0 + 64 < 1024) STAGE_QKV(cur ^ 1, k0 + 64);
#pragma unroll
      for (int kk = 0; kk < 2; ++kk) {
        bf16x8 bf[3];
        const int rowB = (w << 4) + lr;
        const int gB = ((kk * 4 + lq) ^ (rowB & 7)) * 8;
#pragma unroll
        for (int e = 0; e < 3; ++e)
          bf[e] = *(const bf16x8*)&sh.st.B[cur][e][rowB][gB];
#pragma unroll
        for (int mt = 0; mt < 4; ++mt) {
          const int rowA = (mt << 4) + lr;
          const int gA = ((kk * 4 + lq) ^ (rowA & 7)) * 8;
          bf16x8 af0 = *(const bf16x8*)&sh.st.A[cur][0][rowA][gA];
          bf16x8 af1 = *(const bf16x8*)&sh.st.A[cur][1][rowA][gA];
#pragma unroll
          for (int e = 0; e < 3; ++e) {
            acc[e][0][mt] = __builtin_amdgcn_mfma_f32_16x16x32_bf16(af0, bf[e], acc[e][0][mt], 0, 0, 0);
            acc[e][1][mt] = __builtin_amdgcn_mfma_f32_16x16x32_bf16(af1, bf[e], acc[e][1][mt], 0, 0, 0);
          }
        }
      }
      __syncthreads();                    // ONE barrier per step
      cur ^= 1;
    }
#undef STAGE_QKV
  } else {
    // fp32 fallback (dead in practice): single-buffer, linear, 2-barrier
    const float* Xf = (const float*)Xv;
    const float* Wf = (const float*)Wv;
    const int r = t >> 2, cc = (t & 3) * 16;
    for (int k0 = 0; k0 < 1024; k0 += 64) {
      __syncthreads();
#pragma unroll
      for (int ee = 0; ee < 16; ++ee) {
        sh.st.A[0][0][r][cc + ee] = f2b(Xf[(long)(m0 + r) * 1024 + k0 + cc + ee]);
        sh.st.A[0][1][r][cc + ee] = f2b(Xf[(long)(m0 + 64 + r) * 1024 + k0 + cc + ee]);
        sh.st.B[0][0][r][cc + ee] = f2b(Wf[(long)(n0h + r) * 1024 + k0 + cc + ee]);
        sh.st.B[0][1][r][cc + ee] = f2b(Wf[(long)(n0h + r) * 1024 + 1048576 + k0 + cc + ee]);
        sh.st.B[0][2][r][cc + ee] = f2b(Wf[(long)(n0h + r) * 1024 + 2097152 + k0 + cc + ee]);
      }
      __syncthreads();
#pragma unroll
      for (int kk = 0; kk < 2; ++kk) {
        bf16x8 bf[3];
        const int rowB = (w << 4) + lr;
#pragma unroll
        for (int e = 0; e < 3; ++e)
          bf[e] = *(const bf16x8*)&sh.st.B[0][e][rowB][kk * 32 + lq * 8];
#pragma unroll
        for (int mt = 0; mt < 4; ++mt) {
          bf16x8 af0 = *(const bf16x8*)&sh.st.A[0][0][(mt << 4) + lr][kk * 32 + lq * 8];
          bf16x8 af1 = *(const bf16x8*)&sh.st.A[0][1][(mt << 4) + lr][kk * 32 + lq * 8];
#pragma unroll
          for (int e = 0; e < 3; ++e) {
            acc[e][0][mt] = __builtin_amdgcn_mfma_f32_16x16x32_bf16(af0, bf[e], acc[e][0][mt], 0, 0, 0);
            acc[e][1][mt] = __builtin_amdgcn_mfma_f32_16x16x32_bf16(af1, bf[e], acc[e][1][mt], 0, 0, 0);
          }
        }
      }
    }
  }

  // epilogue: 6x Cs round-trip (R12-verbatim; Cs unioned over staging)
  for (int f = 0; f < 2; ++f) {
    const int m0f = m0 + f * 64;
    for (int e = 0; e < 3; ++e) {
      __syncthreads();
      {
        const int col = (w << 4) + lr;
#pragma unroll
        for (int mt = 0; mt < 4; ++mt)
#pragma unroll
          for (int i = 0; i < 4; ++i)
            sh.Cs[mt * 16 + lq * 4 + i][col] = acc[e][f][mt][i];
      }
      __syncthreads();
      if (e == 2) {
        const int sx = t & 63, dh0 = (t >> 6) * 16;
        const int m = m0f + sx, b = m >> 11, s = m & 2047;
        const long hb = (long)(b * 16 + h) * 64;
#pragma unroll
        for (int u = 0; u < 16; ++u) {
          int dh = dh0 + u;
          Vo[(hb + dh) * 2048 + s] = f2b(sh.Cs[sx][dh]);
        }
      } else {
        const int r = t >> 2, dh0 = (t & 3) * 16;
        const int m = m0f + r, b = m >> 11, s = m & 2047;
        const int obase = ((b * 16 + h) * 2048 + s) * 64;
        u16* O = (e == 0) ? Qo : Ko;
#pragma unroll
        for (int u = 0; u < 16; ++u) {
          int dh = dh0 + u;
          float v  = sh.Cs[r][dh];
          float vp = sh.Cs[r][dh ^ 32];
          float sign = (dh < 32) ? -1.0f : 1.0f;
          float fr  = __expf((float)(dh & 31) * -0.28782314f);
          float ang = (float)s * fr;
          float sn = __sinf(ang), cs = __cosf(ang);
          O[obase + dh] = f2b(v * cs + sign * vp * sn);
        }
      }
    }
  }
}

// ---------------------------------------------------------------------------
// Per-tile attention body (R9-proven math, factored; per-tile qt/state).
// ---------------------------------------------------------------------------
__device__ __forceinline__ void attn_tile(u16 QP[64][72], u16 Ks[64][72],
                                          u16 Vt[64][72], const bf16x8 qf[2],
                                          f32x4 o_acc[4], float& m_i, float& l_i,
                                          int kt, int qt_tile, int w, int lr,
                                          int lq, int lq4, int base16, int qrow_l) {
  f32x4 sa[4] = {};
#pragma unroll
  for (int mb = 0; mb < 4; ++mb)
#pragma unroll
    for (int kk = 0; kk < 2; ++kk) {
      bf16x8 kf = *(const bf16x8*)&Ks[mb * 16 + lr][kk * 32 + lq * 8];
      sa[mb] = __builtin_amdgcn_mfma_f32_16x16x32_bf16(kf, qf[kk], sa[mb], 0, 0, 0);
    }
  float sc[4][4];
  float m_new = m_i;
#pragma unroll
  for (int mb = 0; mb < 4; ++mb)
#pragma unroll
    for (int i = 0; i < 4; ++i) {
      float sv = sa[mb][i] * 0.125f;
      if (kt == qt_tile && (mb * 16 + lq4 + i) > qrow_l) sv = -3.0e4f;
      sc[mb][i] = sv;
      m_new = fmaxf(m_new, sv);
    }
  m_new = fmaxf(m_new, __shfl_xor(m_new, 16));
  m_new = fmaxf(m_new, __shfl_xor(m_new, 32));
  float alpha = __expf(m_i - m_new);
  m_i = m_new;
  float p[4][4], sm = 0.f;
#pragma unroll
  for (int mb = 0; mb < 4; ++mb)
#pragma unroll
    for (int i = 0; i < 4; ++i) { p[mb][i] = __expf(sc[mb][i] - m_new); sm += p[mb][i]; }
  sm += __shfl_xor(sm, 16);
  sm += __shfl_xor(sm, 32);
  l_i = l_i * alpha + sm;
#pragma unroll
  for (int mb = 0; mb < 4; ++mb) {
    uint2 pk;
    pk.x = (uint32_t)f2b(p[mb][0]) | ((uint32_t)f2b(p[mb][1]) << 16);
    pk.y = (uint32_t)f2b(p[mb][2]) | ((uint32_t)f2b(p[mb][3]) << 16);
    *(uint2*)&QP[w * 16 + lr][mb * 16 + lq4] = pk;
  }
#pragma unroll
  for (int i = 0; i < 4; ++i) {
    float ai = __shfl(alpha, base16 | (lq4 + i));
    o_acc[0][i] *= ai; o_acc[1][i] *= ai;
    o_acc[2][i] *= ai; o_acc[3][i] *= ai;
  }
  asm volatile("s_waitcnt lgkmcnt(0)" ::: "memory");
#pragma unroll
  for (int kk = 0; kk < 2; ++kk) {
    bf16x8 pf = *(const bf16x8*)&QP[w * 16 + lr][kk * 32 + lq * 8];
#pragma unroll
    for (int nb = 0; nb < 4; ++nb) {
      bf16x8 vf = *(const bf16x8*)&Vt[nb * 16 + lr][kk * 32 + lq * 8];
      o_acc[nb] = __builtin_amdgcn_mfma_f32_16x16x32_bf16(pf, vf, o_acc[nb], 0, 0, 0);
    }
  }
}

// ---------------------------------------------------------------------------
// Kernel 2: causal flash attention — REVERTED to R8/R9-proven version
// (K/V LDS dbuf + reg prefetch, 1 barrier/kt, T1 XCD remap). R10's
// direct-from-global MFMA operands exposed L2 latency per fragment (-2x).
// ---------------------------------------------------------------------------
__global__ __launch_bounds__(256) void k_attn(const u16* __restrict__ Q,
                                              const u16* __restrict__ K,
                                              const u16* __restrict__ V,
                                              u16* __restrict__ AO) {
  __shared__ u16 QP[64][72];
  __shared__ u16 Ks[2][64][72];
  __shared__ u16 Vt[2][64][72];
  // XCD swizzle: bijective (512 % 8 == 0). bh inner (4 per XCD), q-pair outer.
  const int id = blockIdx.y * 16 + blockIdx.x;
  const int xcd = id & 7, p = id >> 3;
  const int bh = (xcd << 2) | (p & 3);  // 4 bh per XCD
  const int qp = p >> 2;                // q-pair 0..15
  const int qtA = 31 - qp;              // 16..31
  const int qtB = qp;                   // 0..15  (qtB < qtA always)
  const int b = bh >> 4, h = bh & 15;
  const u16* Qg = Q + (bh * 2048) * 64;
  const u16* Kg = K + bh * 2048 * 64;
  const u16* Vg = V + (long)bh * 64 * 2048;
  const int t = threadIdx.x, w = t >> 6, lane = t & 63;
  const int lr = lane & 15, lq = lane >> 4;
  const int lq4 = lq * 4;
  const int base16 = lane & 48;
  const int r0 = t >> 3, c0 = (t & 7) * 8;
  const int qrow_l = w * 16 + lr;

  // kt=0 K/V loads issue first: overlap the Q staging below.
  uint4 pk0 = *(const uint4*)&Kg[r0 * 64 + c0];
  uint4 pk1 = *(const uint4*)&Kg[(r0 + 32) * 64 + c0];
  uint4 pv0 = *(const uint4*)&Vg[r0 * 2048 + c0];
  uint4 pv1 = *(const uint4*)&Vg[(r0 + 32) * 2048 + c0];

  bf16x8 qfA[2], qfB[2];
  *(uint4*)&QP[r0][c0]      = *(const uint4*)&Qg[(qtA * 64 + r0) * 64 + c0];
  *(uint4*)&QP[r0 + 32][c0] = *(const uint4*)&Qg[(qtA * 64 + r0 + 32) * 64 + c0];
  __syncthreads();
#pragma unroll
  for (int kk = 0; kk < 2; ++kk)
    qfA[kk] = *(const bf16x8*)&QP[w * 16 + lr][kk * 32 + lq * 8];
  __syncthreads();
  *(uint4*)&QP[r0][c0]      = *(const uint4*)&Qg[(qtB * 64 + r0) * 64 + c0];
  *(uint4*)&QP[r0 + 32][c0] = *(const uint4*)&Qg[(qtB * 64 + r0 + 32) * 64 + c0];
  __syncthreads();
#pragma unroll
  for (int kk = 0; kk < 2; ++kk)
    qfB[kk] = *(const bf16x8*)&QP[w * 16 + lr][kk * 32 + lq * 8];

  // tile 0 -> buf0; tile 1 -> regs (qtA >= 16 so tile 1 always exists)
  *(uint4*)&Ks[0][r0][c0]      = pk0;
  *(uint4*)&Ks[0][r0 + 32][c0] = pk1;
  *(uint4*)&Vt[0][r0][c0]      = pv0;
  *(uint4*)&Vt[0][r0 + 32][c0] = pv1;
  pk0 = *(const uint4*)&Kg[(64 + r0) * 64 + c0];
  pk1 = *(const uint4*)&Kg[(64 + r0 + 32) * 64 + c0];
  pv0 = *(const uint4*)&Vg[r0 * 2048 + 64 + c0];
  pv1 = *(const uint4*)&Vg[(r0 + 32) * 2048 + 64 + c0];
  __syncthreads();                      // buf0 visible everywhere

  float m_iA = -3.0e4f, l_iA = 0.f, m_iB = -3.0e4f, l_iB = 0.f;
  f32x4 o_accA[4] = {}, o_accB[4] = {};

  int cur = 0;
  for (int kt = 0; kt <= qtA; ++kt) {
    if (kt + 1 <= qtA) {                // write tile kt+1 -> other buffer
      *(uint4*)&Ks[cur ^ 1][r0][c0]      = pk0;
      *(uint4*)&Ks[cur ^ 1][r0 + 32][c0] = pk1;
      *(uint4*)&Vt[cur ^ 1][r0][c0]      = pv0;
      *(uint4*)&Vt[cur ^ 1][r0 + 32][c0] = pv1;
    }
    if (kt + 2 <= qtA) {                // prefetch tile kt+2
      const int kn = kt + 2;
      pk0 = *(const uint4*)&Kg[(kn * 64 + r0) * 64 + c0];
      pk1 = *(const uint4*)&Kg[(kn * 64 + r0 + 32) * 64 + c0];
      pv0 = *(const uint4*)&Vg[r0 * 2048 + kn * 64 + c0];
      pv1 = *(const uint4*)&Vg[(r0 + 32) * 2048 + kn * 64 + c0];
    }

    attn_tile(QP, Ks[cur], Vt[cur], qfA, o_accA, m_iA, l_iA, kt, qtA,
              w, lr, lq, lq4, base16, qrow_l);
    if (kt <= qtB) {
      asm volatile("s_waitcnt lgkmcnt(0)" ::: "memory");
      attn_tile(QP, Ks[cur], Vt[cur], qfB, o_accB, m_iB, l_iB, kt, qtB,
                w, lr, lq, lq4, base16, qrow_l);
    }
    __syncthreads();                    // ONE barrier per kt
    cur ^= 1;
  }
  float linvA = 1.0f / l_iA, linvB = 1.0f / l_iB;
#pragma unroll
  for (int i = 0; i < 4; ++i) {
    float invA = __shfl(linvA, base16 | (lq4 + i));
    float invB = __shfl(linvB, base16 | (lq4 + i));
    int rowA = qtA * 64 + w * 16 + lq4 + i;
    int rowB = qtB * 64 + w * 16 + lq4 + i;
    int obA = (b * 2048 + rowA) * 1024 + h * 64;
    int obB = (b * 2048 + rowB) * 1024 + h * 64;
#pragma unroll
    for (int nb = 0; nb < 4; ++nb) {
      AO[obA + nb * 16 + lr] = f2b(o_accA[nb][i] * invA);
      AO[obB + nb * 16 + lr] = f2b(o_accB[nb][i] * invB);
    }
  }
}

// ---------------------------------------------------------------------------
// Kernel 3: out = ao @ w_out^T — R9-VERBATIM (BK=64, gload_lds dbuf, granule
// XOR swizzle both sides, T1 XCD remap).
// ---------------------------------------------------------------------------
__global__ __launch_bounds__(256) void k_gemm_out(const u16* __restrict__ A,
                                                  const void* __restrict__ Bv,
                                                  void* __restrict__ Cv) {
  __shared__ u16 As[2][64][64];       // [buf]       16 KB
  __shared__ u16 Bs[2][2][64][64];    // [buf][half] 32 KB
  __shared__ int cnt_sh;
  const int t = threadIdx.x, w = t >> 6, lane = t & 63;
  const int mode = probe_mode((const u16*)Bv, t, &cnt_sh);
  // XCD swizzle: bijective (512 % 8 == 0). m inner (8 per XCD), n outer.
  const int id = blockIdx.y * 8 + blockIdx.x;
  const int xcd = id & 7, p = id >> 3;
  const int n0 = (p >> 3) * 128;
  const int m0 = ((xcd << 3) | (p & 7)) * 64;
  const int lr = lane & 15, lq = lane >> 4;
  f32x4 acc[2][4] = {};               // [n-half][mt]

  if (mode == 0) {
    const u16* Bp = (const u16*)Bv;
    const int lrow = lane >> 3;           // 0..7
    const int lg   = (lane & 7) ^ lrow;   // pre-swizzled source granule
    const long ar0 = (long)(m0 + w * 8 + lrow) * 1024 + lg * 8;
    const long ar1 = (long)(m0 + w * 8 + 32 + lrow) * 1024 + lg * 8;
    const long br00 = (long)(n0 + w * 8 + lrow) * 1024 + lg * 8;
    const long br01 = (long)(n0 + w * 8 + 32 + lrow) * 1024 + lg * 8;
    const long br10 = br00 + 65536;     // +64 rows of w_out (half 1)
    const long br11 = br01 + 65536;
#define STAGE_OUT(buf, kk)                                                     \
    do {                                                                       \
      GLOAD16(A + ar0 + (kk),   &As[buf][w * 8][0]);                           \
      GLOAD16(A + ar1 + (kk),   &As[buf][w * 8 + 32][0]);                      \
      GLOAD16(Bp + br00 + (kk), &Bs[buf][0][w * 8][0]);                        \
      GLOAD16(Bp + br01 + (kk), &Bs[buf][0][w * 8 + 32][0]);                   \
      GLOAD16(Bp + br10 + (kk), &Bs[buf][1][w * 8][0]);                        \
      GLOAD16(Bp + br11 + (kk), &Bs[buf][1][w * 8 + 32][0]);                   \
    } while (0)
    STAGE_OUT(0, 0);
    asm volatile("s_waitcnt vmcnt(0)" ::: "memory");
    __syncthreads();
    int cur = 0;
    for (int k0 = 0; k0 < 1024; k0 += 64) {
      if (k0 + 64 < 1024) STAGE_OUT(cur ^ 1, k0 + 64);
#pragma unroll
      for (int kk = 0; kk < 2; ++kk) {
        bf16x8 bfx[2];
        const int rowB = (w << 4) + lr;
        const int gB = ((kk * 4 + lq) ^ (rowB & 7)) * 8;
#pragma unroll
        for (int e = 0; e < 2; ++e)
          bfx[e] = *(const bf16x8*)&Bs[cur][e][rowB][gB];
#pragma unroll
        for (int mt = 0; mt < 4; ++mt) {
          const int rowA = (mt << 4) + lr;
          const int gA = ((kk * 4 + lq) ^ (rowA & 7)) * 8;
          bf16x8 af = *(const bf16x8*)&As[cur][rowA][gA];
#pragma unroll
          for (int e = 0; e < 2; ++e)
            acc[e][mt] = __builtin_amdgcn_mfma_f32_16x16x32_bf16(af, bfx[e], acc[e][mt], 0, 0, 0);
        }
      }
      __syncthreads();
      cur ^= 1;
    }
#undef STAGE_OUT
  } else {
    // fp32-W fallback (dead in practice): single-buffer, linear (no swizzle),
    // 2-barrier, BK=64. A is always bf16 (our ao buffer).
    const float* Bf = (const float*)Bv;
    const int r = t >> 2, cc = (t & 3) * 16;
    for (int k0 = 0; k0 < 1024; k0 += 64) {
      __syncthreads();
      *(uint4*)&As[0][r][cc]     = *(const uint4*)(A + (long)(m0 + r) * 1024 + k0 + cc);
      *(uint4*)&As[0][r][cc + 8] = *(const uint4*)(A + (long)(m0 + r) * 1024 + k0 + cc + 8);
#pragma unroll
      for (int ee = 0; ee < 16; ++ee) {
        Bs[0][0][r][cc + ee] = f2b(Bf[(long)(n0 + r) * 1024 + k0 + cc + ee]);
        Bs[0][1][r][cc + ee] = f2b(Bf[(long)(n0 + 64 + r) * 1024 + k0 + cc + ee]);
      }
      __syncthreads();
#pragma unroll
      for (int kk = 0; kk < 2; ++kk) {
        bf16x8 bfx[2];
        const int rowB = (w << 4) + lr;
#pragma unroll
        for (int e = 0; e < 2; ++e)
          bfx[e] = *(const bf16x8*)&Bs[0][e][rowB][kk * 32 + lq * 8];
#pragma unroll
        for (int mt = 0; mt < 4; ++mt) {
          bf16x8 af = *(const bf16x8*)&As[0][(mt << 4) + lr][kk * 32 + lq * 8];
#pragma unroll
          for (int e = 0; e < 2; ++e)
            acc[e][mt] = __builtin_amdgcn_mfma_f32_16x16x32_bf16(af, bfx[e], acc[e][mt], 0, 0, 0);
        }
      }
    }
  }
#pragma unroll
  for (int e = 0; e < 2; ++e) {
    const int col = n0 + e * 64 + (w << 4) + lr;
    if (mode == 0) {
      u16* C = (u16*)Cv;
#pragma unroll
      for (int mt = 0; mt < 4; ++mt)
#pragma unroll
        for (int i = 0; i < 4; ++i)
          C[(m0 + mt * 16 + lq * 4 + i) * 1024 + col] = f2b(acc[e][mt][i]);
    } else {
      float* C = (float*)Cv;
#pragma unroll
      for (int mt = 0; mt < 4; ++mt)
#pragma unroll
        for (int i = 0; i < 4; ++i)
          C[(m0 + mt * 16 + lq * 4 + i) * 1024 + col] = acc[e][mt][i];
    }
  }
}

// ---------------------------------------------------------------------------
extern "C" void kernel_launch(void* const* d_in, const int* in_sizes, int n_in,
                              void* d_out, int out_size, void* d_ws, size_t ws_size,
                              hipStream_t stream) {
  const void* x    = d_in[0];   // (4096,1024)
  const void* wqkv = d_in[1];   // (3072,1024)
  const void* wout = d_in[2];   // (1024,1024)

  // ws layout: [reserved 256B][q 8.39MB][k 8.39MB][v^T 8.39MB][ao]
  u16* qb = (u16*)((char*)d_ws + 256);
  u16* kb = qb + 4194304;
  u16* vb = kb + 4194304;
  u16* ao = vb + 4194304;

  k_qkv_rope<<<dim3(16, 32), 256, 0, stream>>>(x, wqkv, qb, kb, vb);
  k_attn    <<<dim3(16, 32), 256, 0, stream>>>(qb, kb, vb, ao);
  k_gemm_out<<<dim3(8, 64), 256, 0, stream>>>(ao, wout, d_out);
}

// Round 12
// 201.808 us; speedup vs baseline: 2.0317x; 2.0317x over previous
//
#include <hip/hip_runtime.h>
#include <stdint.h>

typedef uint16_t u16;
typedef __attribute__((ext_vector_type(8))) short bf16x8;
typedef __attribute__((ext_vector_type(4))) float f32x4;

__device__ inline u16 f2b(float f) {          // fp32 -> bf16 RNE
  uint32_t u = __float_as_uint(f);
  u += 0x7FFF + ((u >> 16) & 1);
  return (u16)(u >> 16);
}
__device__ inline float b2f(u16 h) {          // bf16 -> fp32 exact
  return __uint_as_float(((uint32_t)h) << 16);
}

// Async global->LDS DMA, 16B per lane (used by k_gemm_out only).
typedef __attribute__((address_space(1))) void gvoid;
typedef __attribute__((address_space(3))) void lvoid;
#define GLOAD16(gp, lp)                                                        \
  __builtin_amdgcn_global_load_lds((gvoid*)(gp), (lvoid*)(lp), 16, 0, 0)

// ---------------------------------------------------------------------------
// Inline dtype probe: mode 0 = bf16, 1 = fp32 (R4-proven).
// ---------------------------------------------------------------------------
__device__ __forceinline__ int probe_mode(const u16* __restrict__ P, int t,
                                          int* cnt_sh) {
  if (t == 0) *cnt_sh = 0;
  __syncthreads();
  float av = fabsf(b2f(P[t * 2]));
  if (av >= 1000.0f) atomicAdd(cnt_sh, 1);
  __syncthreads();
  return (*cnt_sh > 16) ? 1 : 0;
}

// ---------------------------------------------------------------------------
// Kernel 1: qkv = x @ w_qkv^T — PROVEN BEST (R5 loop + T1 XCD remap, BK=32,
// padded [64][40] LDS, dbuf, 1 barrier/step; 62-70 us, FETCH 57 MB).
// R11's BK=64/gload_lds port regressed 4x (LDS 82KB -> 1 block/CU; granule
// XOR conflicts 105.9M at this read shape) — reverted.
// ---------------------------------------------------------------------------
__global__ __launch_bounds__(256) void k_qkv_rope(const void* __restrict__ Xv,
                                                  const void* __restrict__ Wv,
                                                  u16* __restrict__ Qo,
                                                  u16* __restrict__ Ko,
                                                  u16* __restrict__ Vo) {
  __shared__ u16 As[2][2][64][40];        // [buf][m-half]
  __shared__ u16 Bs[2][3][64][40];        // [buf][e]
  __shared__ float Cs[64][66];
  __shared__ int cnt_sh;
  const int t = threadIdx.x, w = t >> 6, lane = t & 63;
  const int mode = probe_mode((const u16*)Xv, t, &cnt_sh);
  // XCD swizzle: id in [0,512), xcd = id&7, p = id>>3; h = p>>2 (outer),
  // m-tile = xcd*4 + (p&3) (inner). Bijective since 512 % 8 == 0.
  const int id = blockIdx.y * 16 + blockIdx.x;
  const int xcd = id & 7, p = id >> 3;
  const int h = p >> 2;                   // head 0..15
  const int n0h = h * 64;
  const int m0 = ((xcd << 2) | (p & 3)) << 7;   // m-tile*128
  const int lr = lane & 15, lq = lane >> 4;
  f32x4 acc[3][2][4] = {};                // [e][m-half][mt]
  const int rA = t >> 2, cA = (t & 3) * 8;
  const int aoff0 = (m0 + rA) * 1024 + cA;
  const int aoff1 = (m0 + 64 + rA) * 1024 + cA;
  const int boff0 = (n0h + rA) * 1024 + cA;

  if (mode == 0) {
    const u16* Xp = (const u16*)Xv;
    const u16* Wp = (const u16*)Wv;
    // tile 0 -> regs -> buf0
    uint4 pa0 = *(const uint4*)(Xp + aoff0);
    uint4 pa1 = *(const uint4*)(Xp + aoff1);
    uint4 pb0 = *(const uint4*)(Wp + boff0);
    uint4 pb1 = *(const uint4*)(Wp + boff0 + 1048576);
    uint4 pb2 = *(const uint4*)(Wp + boff0 + 2097152);
    *(uint4*)&As[0][0][rA][cA] = pa0;
    *(uint4*)&As[0][1][rA][cA] = pa1;
    *(uint4*)&Bs[0][0][rA][cA] = pb0;
    *(uint4*)&Bs[0][1][rA][cA] = pb1;
    *(uint4*)&Bs[0][2][rA][cA] = pb2;
    // tile 1 -> regs
    pa0 = *(const uint4*)(Xp + aoff0 + 32);
    pa1 = *(const uint4*)(Xp + aoff1 + 32);
    pb0 = *(const uint4*)(Wp + boff0 + 32);
    pb1 = *(const uint4*)(Wp + boff0 + 1048576 + 32);
    pb2 = *(const uint4*)(Wp + boff0 + 2097152 + 32);
    __syncthreads();                      // buf0 visible, tile-1 regs resident
    int cur = 0;
    for (int k0 = 0; k0 < 1024; k0 += 32) {
      if (k0 + 32 < 1024) {               // write tile k+1 -> other buffer
        *(uint4*)&As[cur ^ 1][0][rA][cA] = pa0;
        *(uint4*)&As[cur ^ 1][1][rA][cA] = pa1;
        *(uint4*)&Bs[cur ^ 1][0][rA][cA] = pb0;
        *(uint4*)&Bs[cur ^ 1][1][rA][cA] = pb1;
        *(uint4*)&Bs[cur ^ 1][2][rA][cA] = pb2;
      }
      if (k0 + 64 < 1024) {               // prefetch tile k+2
        const int kn = k0 + 64;
        pa0 = *(const uint4*)(Xp + aoff0 + kn);
        pa1 = *(const uint4*)(Xp + aoff1 + kn);
        pb0 = *(const uint4*)(Wp + boff0 + kn);
        pb1 = *(const uint4*)(Wp + boff0 + 1048576 + kn);
        pb2 = *(const uint4*)(Wp + boff0 + 2097152 + kn);
      }
      bf16x8 bf[3];                       // compute from buf[cur]
#pragma unroll
      for (int e = 0; e < 3; ++e)
        bf[e] = *(const bf16x8*)&Bs[cur][e][(w << 4) + lr][lq * 8];
#pragma unroll
      for (int mt = 0; mt < 4; ++mt) {
        bf16x8 af0 = *(const bf16x8*)&As[cur][0][(mt << 4) + lr][lq * 8];
        bf16x8 af1 = *(const bf16x8*)&As[cur][1][(mt << 4) + lr][lq * 8];
#pragma unroll
        for (int e = 0; e < 3; ++e) {
          acc[e][0][mt] = __builtin_amdgcn_mfma_f32_16x16x32_bf16(af0, bf[e], acc[e][0][mt], 0, 0, 0);
          acc[e][1][mt] = __builtin_amdgcn_mfma_f32_16x16x32_bf16(af1, bf[e], acc[e][1][mt], 0, 0, 0);
        }
      }
      __syncthreads();                    // ONE barrier per step
      cur ^= 1;
    }
  } else {
    // fp32 fallback (dead in practice): single-buffer, 2-barrier
    for (int k0 = 0; k0 < 1024; k0 += 32) {
      __syncthreads();
      const float* Xf = (const float*)Xv;
      const float* Wf = (const float*)Wv;
#pragma unroll
      for (int ee = 0; ee < 8; ++ee) {
        As[0][0][rA][cA + ee] = f2b(Xf[aoff0 + k0 + ee]);
        As[0][1][rA][cA + ee] = f2b(Xf[aoff1 + k0 + ee]);
        Bs[0][0][rA][cA + ee] = f2b(Wf[boff0 + k0 + ee]);
        Bs[0][1][rA][cA + ee] = f2b(Wf[boff0 + 1048576 + k0 + ee]);
        Bs[0][2][rA][cA + ee] = f2b(Wf[boff0 + 2097152 + k0 + ee]);
      }
      __syncthreads();
      bf16x8 bf[3];
#pragma unroll
      for (int e = 0; e < 3; ++e)
        bf[e] = *(const bf16x8*)&Bs[0][e][(w << 4) + lr][lq * 8];
#pragma unroll
      for (int mt = 0; mt < 4; ++mt) {
        bf16x8 af0 = *(const bf16x8*)&As[0][0][(mt << 4) + lr][lq * 8];
        bf16x8 af1 = *(const bf16x8*)&As[0][1][(mt << 4) + lr][lq * 8];
#pragma unroll
        for (int e = 0; e < 3; ++e) {
          acc[e][0][mt] = __builtin_amdgcn_mfma_f32_16x16x32_bf16(af0, bf[e], acc[e][0][mt], 0, 0, 0);
          acc[e][1][mt] = __builtin_amdgcn_mfma_f32_16x16x32_bf16(af1, bf[e], acc[e][1][mt], 0, 0, 0);
        }
      }
    }
  }

  // epilogue: 6x Cs round-trip (R12-verbatim)
  for (int f = 0; f < 2; ++f) {
    const int m0f = m0 + f * 64;
    for (int e = 0; e < 3; ++e) {
      __syncthreads();
      {
        const int col = (w << 4) + lr;
#pragma unroll
        for (int mt = 0; mt < 4; ++mt)
#pragma unroll
          for (int i = 0; i < 4; ++i)
            Cs[mt * 16 + lq * 4 + i][col] = acc[e][f][mt][i];
      }
      __syncthreads();
      if (e == 2) {
        const int sx = t & 63, dh0 = (t >> 6) * 16;
        const int m = m0f + sx, b = m >> 11, s = m & 2047;
        const long hb = (long)(b * 16 + h) * 64;
#pragma unroll
        for (int u = 0; u < 16; ++u) {
          int dh = dh0 + u;
          Vo[(hb + dh) * 2048 + s] = f2b(Cs[sx][dh]);
        }
      } else {
        const int r = t >> 2, dh0 = (t & 3) * 16;
        const int m = m0f + r, b = m >> 11, s = m & 2047;
        const int obase = ((b * 16 + h) * 2048 + s) * 64;
        u16* O = (e == 0) ? Qo : Ko;
#pragma unroll
        for (int u = 0; u < 16; ++u) {
          int dh = dh0 + u;
          float v  = Cs[r][dh];
          float vp = Cs[r][dh ^ 32];
          float sign = (dh < 32) ? -1.0f : 1.0f;
          float fr  = __expf((float)(dh & 31) * -0.28782314f);
          float ang = (float)s * fr;
          float sn = __sinf(ang), cs = __cosf(ang);
          O[obase + dh] = f2b(v * cs + sign * vp * sn);
        }
      }
    }
  }
}

// ---------------------------------------------------------------------------
// Per-tile attention body (R9-proven math, factored; per-tile qt/state).
// ---------------------------------------------------------------------------
__device__ __forceinline__ void attn_tile(u16 QP[64][72], u16 Ks[64][72],
                                          u16 Vt[64][72], const bf16x8 qf[2],
                                          f32x4 o_acc[4], float& m_i, float& l_i,
                                          int kt, int qt_tile, int w, int lr,
                                          int lq, int lq4, int base16, int qrow_l) {
  f32x4 sa[4] = {};
#pragma unroll
  for (int mb = 0; mb < 4; ++mb)
#pragma unroll
    for (int kk = 0; kk < 2; ++kk) {
      bf16x8 kf = *(const bf16x8*)&Ks[mb * 16 + lr][kk * 32 + lq * 8];
      sa[mb] = __builtin_amdgcn_mfma_f32_16x16x32_bf16(kf, qf[kk], sa[mb], 0, 0, 0);
    }
  float sc[4][4];
  float m_new = m_i;
#pragma unroll
  for (int mb = 0; mb < 4; ++mb)
#pragma unroll
    for (int i = 0; i < 4; ++i) {
      float sv = sa[mb][i] * 0.125f;
      if (kt == qt_tile && (mb * 16 + lq4 + i) > qrow_l) sv = -3.0e4f;
      sc[mb][i] = sv;
      m_new = fmaxf(m_new, sv);
    }
  m_new = fmaxf(m_new, __shfl_xor(m_new, 16));
  m_new = fmaxf(m_new, __shfl_xor(m_new, 32));
  float alpha = __expf(m_i - m_new);
  m_i = m_new;
  float p[4][4], sm = 0.f;
#pragma unroll
  for (int mb = 0; mb < 4; ++mb)
#pragma unroll
    for (int i = 0; i < 4; ++i) { p[mb][i] = __expf(sc[mb][i] - m_new); sm += p[mb][i]; }
  sm += __shfl_xor(sm, 16);
  sm += __shfl_xor(sm, 32);
  l_i = l_i * alpha + sm;
#pragma unroll
  for (int mb = 0; mb < 4; ++mb) {
    uint2 pk;
    pk.x = (uint32_t)f2b(p[mb][0]) | ((uint32_t)f2b(p[mb][1]) << 16);
    pk.y = (uint32_t)f2b(p[mb][2]) | ((uint32_t)f2b(p[mb][3]) << 16);
    *(uint2*)&QP[w * 16 + lr][mb * 16 + lq4] = pk;
  }
#pragma unroll
  for (int i = 0; i < 4; ++i) {
    float ai = __shfl(alpha, base16 | (lq4 + i));
    o_acc[0][i] *= ai; o_acc[1][i] *= ai;
    o_acc[2][i] *= ai; o_acc[3][i] *= ai;
  }
  asm volatile("s_waitcnt lgkmcnt(0)" ::: "memory");
#pragma unroll
  for (int kk = 0; kk < 2; ++kk) {
    bf16x8 pf = *(const bf16x8*)&QP[w * 16 + lr][kk * 32 + lq * 8];
#pragma unroll
    for (int nb = 0; nb < 4; ++nb) {
      bf16x8 vf = *(const bf16x8*)&Vt[nb * 16 + lr][kk * 32 + lq * 8];
      o_acc[nb] = __builtin_amdgcn_mfma_f32_16x16x32_bf16(pf, vf, o_acc[nb], 0, 0, 0);
    }
  }
}

// ---------------------------------------------------------------------------
// Kernel 2: causal flash attention — PROVEN BEST (K/V LDS dbuf + reg
// prefetch, 1 barrier/kt, T1 XCD remap; ~60 us).
// ---------------------------------------------------------------------------
__global__ __launch_bounds__(256) void k_attn(const u16* __restrict__ Q,
                                              const u16* __restrict__ K,
                                              const u16* __restrict__ V,
                                              u16* __restrict__ AO) {
  __shared__ u16 QP[64][72];
  __shared__ u16 Ks[2][64][72];
  __shared__ u16 Vt[2][64][72];
  // XCD swizzle: bijective (512 % 8 == 0). bh inner (4 per XCD), q-pair outer.
  const int id = blockIdx.y * 16 + blockIdx.x;
  const int xcd = id & 7, p = id >> 3;
  const int bh = (xcd << 2) | (p & 3);  // 4 bh per XCD
  const int qp = p >> 2;                // q-pair 0..15
  const int qtA = 31 - qp;              // 16..31
  const int qtB = qp;                   // 0..15  (qtB < qtA always)
  const int b = bh >> 4, h = bh & 15;
  const u16* Qg = Q + (bh * 2048) * 64;
  const u16* Kg = K + bh * 2048 * 64;
  const u16* Vg = V + (long)bh * 64 * 2048;
  const int t = threadIdx.x, w = t >> 6, lane = t & 63;
  const int lr = lane & 15, lq = lane >> 4;
  const int lq4 = lq * 4;
  const int base16 = lane & 48;
  const int r0 = t >> 3, c0 = (t & 7) * 8;
  const int qrow_l = w * 16 + lr;

  // kt=0 K/V loads issue first: overlap the Q staging below.
  uint4 pk0 = *(const uint4*)&Kg[r0 * 64 + c0];
  uint4 pk1 = *(const uint4*)&Kg[(r0 + 32) * 64 + c0];
  uint4 pv0 = *(const uint4*)&Vg[r0 * 2048 + c0];
  uint4 pv1 = *(const uint4*)&Vg[(r0 + 32) * 2048 + c0];

  bf16x8 qfA[2], qfB[2];
  *(uint4*)&QP[r0][c0]      = *(const uint4*)&Qg[(qtA * 64 + r0) * 64 + c0];
  *(uint4*)&QP[r0 + 32][c0] = *(const uint4*)&Qg[(qtA * 64 + r0 + 32) * 64 + c0];
  __syncthreads();
#pragma unroll
  for (int kk = 0; kk < 2; ++kk)
    qfA[kk] = *(const bf16x8*)&QP[w * 16 + lr][kk * 32 + lq * 8];
  __syncthreads();
  *(uint4*)&QP[r0][c0]      = *(const uint4*)&Qg[(qtB * 64 + r0) * 64 + c0];
  *(uint4*)&QP[r0 + 32][c0] = *(const uint4*)&Qg[(qtB * 64 + r0 + 32) * 64 + c0];
  __syncthreads();
#pragma unroll
  for (int kk = 0; kk < 2; ++kk)
    qfB[kk] = *(const bf16x8*)&QP[w * 16 + lr][kk * 32 + lq * 8];

  // tile 0 -> buf0; tile 1 -> regs (qtA >= 16 so tile 1 always exists)
  *(uint4*)&Ks[0][r0][c0]      = pk0;
  *(uint4*)&Ks[0][r0 + 32][c0] = pk1;
  *(uint4*)&Vt[0][r0][c0]      = pv0;
  *(uint4*)&Vt[0][r0 + 32][c0] = pv1;
  pk0 = *(const uint4*)&Kg[(64 + r0) * 64 + c0];
  pk1 = *(const uint4*)&Kg[(64 + r0 + 32) * 64 + c0];
  pv0 = *(const uint4*)&Vg[r0 * 2048 + 64 + c0];
  pv1 = *(const uint4*)&Vg[(r0 + 32) * 2048 + 64 + c0];
  __syncthreads();                      // buf0 visible everywhere

  float m_iA = -3.0e4f, l_iA = 0.f, m_iB = -3.0e4f, l_iB = 0.f;
  f32x4 o_accA[4] = {}, o_accB[4] = {};

  int cur = 0;
  for (int kt = 0; kt <= qtA; ++kt) {
    if (kt + 1 <= qtA) {                // write tile kt+1 -> other buffer
      *(uint4*)&Ks[cur ^ 1][r0][c0]      = pk0;
      *(uint4*)&Ks[cur ^ 1][r0 + 32][c0] = pk1;
      *(uint4*)&Vt[cur ^ 1][r0][c0]      = pv0;
      *(uint4*)&Vt[cur ^ 1][r0 + 32][c0] = pv1;
    }
    if (kt + 2 <= qtA) {                // prefetch tile kt+2
      const int kn = kt + 2;
      pk0 = *(const uint4*)&Kg[(kn * 64 + r0) * 64 + c0];
      pk1 = *(const uint4*)&Kg[(kn * 64 + r0 + 32) * 64 + c0];
      pv0 = *(const uint4*)&Vg[r0 * 2048 + kn * 64 + c0];
      pv1 = *(const uint4*)&Vg[(r0 + 32) * 2048 + kn * 64 + c0];
    }

    attn_tile(QP, Ks[cur], Vt[cur], qfA, o_accA, m_iA, l_iA, kt, qtA,
              w, lr, lq, lq4, base16, qrow_l);
    if (kt <= qtB) {
      asm volatile("s_waitcnt lgkmcnt(0)" ::: "memory");
      attn_tile(QP, Ks[cur], Vt[cur], qfB, o_accB, m_iB, l_iB, kt, qtB,
                w, lr, lq, lq4, base16, qrow_l);
    }
    __syncthreads();                    // ONE barrier per kt
    cur ^= 1;
  }
  float linvA = 1.0f / l_iA, linvB = 1.0f / l_iB;
#pragma unroll
  for (int i = 0; i < 4; ++i) {
    float invA = __shfl(linvA, base16 | (lq4 + i));
    float invB = __shfl(linvB, base16 | (lq4 + i));
    int rowA = qtA * 64 + w * 16 + lq4 + i;
    int rowB = qtB * 64 + w * 16 + lq4 + i;
    int obA = (b * 2048 + rowA) * 1024 + h * 64;
    int obB = (b * 2048 + rowB) * 1024 + h * 64;
#pragma unroll
    for (int nb = 0; nb < 4; ++nb) {
      AO[obA + nb * 16 + lr] = f2b(o_accA[nb][i] * invA);
      AO[obB + nb * 16 + lr] = f2b(o_accB[nb][i] * invB);
    }
  }
}

// ---------------------------------------------------------------------------
// Kernel 3: out = ao @ w_out^T — PROVEN BEST (BK=64, gload_lds dbuf, granule
// XOR swizzle both sides, T1 XCD remap).
// ---------------------------------------------------------------------------
__global__ __launch_bounds__(256) void k_gemm_out(const u16* __restrict__ A,
                                                  const void* __restrict__ Bv,
                                                  void* __restrict__ Cv) {
  __shared__ u16 As[2][64][64];       // [buf]       16 KB
  __shared__ u16 Bs[2][2][64][64];    // [buf][half] 32 KB
  __shared__ int cnt_sh;
  const int t = threadIdx.x, w = t >> 6, lane = t & 63;
  const int mode = probe_mode((const u16*)Bv, t, &cnt_sh);
  // XCD swizzle: bijective (512 % 8 == 0). m inner (8 per XCD), n outer.
  const int id = blockIdx.y * 8 + blockIdx.x;
  const int xcd = id & 7, p = id >> 3;
  const int n0 = (p >> 3) * 128;
  const int m0 = ((xcd << 3) | (p & 7)) * 64;
  const int lr = lane & 15, lq = lane >> 4;
  f32x4 acc[2][4] = {};               // [n-half][mt]

  if (mode == 0) {
    const u16* Bp = (const u16*)Bv;
    const int lrow = lane >> 3;           // 0..7
    const int lg   = (lane & 7) ^ lrow;   // pre-swizzled source granule
    const long ar0 = (long)(m0 + w * 8 + lrow) * 1024 + lg * 8;
    const long ar1 = (long)(m0 + w * 8 + 32 + lrow) * 1024 + lg * 8;
    const long br00 = (long)(n0 + w * 8 + lrow) * 1024 + lg * 8;
    const long br01 = (long)(n0 + w * 8 + 32 + lrow) * 1024 + lg * 8;
    const long br10 = br00 + 65536;     // +64 rows of w_out (half 1)
    const long br11 = br01 + 65536;
#define STAGE_OUT(buf, kk)                                                     \
    do {                                                                       \
      GLOAD16(A + ar0 + (kk),   &As[buf][w * 8][0]);                           \
      GLOAD16(A + ar1 + (kk),   &As[buf][w * 8 + 32][0]);                      \
      GLOAD16(Bp + br00 + (kk), &Bs[buf][0][w * 8][0]);                        \
      GLOAD16(Bp + br01 + (kk), &Bs[buf][0][w * 8 + 32][0]);                   \
      GLOAD16(Bp + br10 + (kk), &Bs[buf][1][w * 8][0]);                        \
      GLOAD16(Bp + br11 + (kk), &Bs[buf][1][w * 8 + 32][0]);                   \
    } while (0)
    STAGE_OUT(0, 0);
    asm volatile("s_waitcnt vmcnt(0)" ::: "memory");
    __syncthreads();
    int cur = 0;
    for (int k0 = 0; k0 < 1024; k0 += 64) {
      if (k0 + 64 < 1024) STAGE_OUT(cur ^ 1, k0 + 64);
#pragma unroll
      for (int kk = 0; kk < 2; ++kk) {
        bf16x8 bfx[2];
        const int rowB = (w << 4) + lr;
        const int gB = ((kk * 4 + lq) ^ (rowB & 7)) * 8;
#pragma unroll
        for (int e = 0; e < 2; ++e)
          bfx[e] = *(const bf16x8*)&Bs[cur][e][rowB][gB];
#pragma unroll
        for (int mt = 0; mt < 4; ++mt) {
          const int rowA = (mt << 4) + lr;
          const int gA = ((kk * 4 + lq) ^ (rowA & 7)) * 8;
          bf16x8 af = *(const bf16x8*)&As[cur][rowA][gA];
#pragma unroll
          for (int e = 0; e < 2; ++e)
            acc[e][mt] = __builtin_amdgcn_mfma_f32_16x16x32_bf16(af, bfx[e], acc[e][mt], 0, 0, 0);
        }
      }
      __syncthreads();
      cur ^= 1;
    }
#undef STAGE_OUT
  } else {
    // fp32-W fallback (dead in practice): single-buffer, linear (no swizzle),
    // 2-barrier, BK=64. A is always bf16 (our ao buffer).
    const float* Bf = (const float*)Bv;
    const int r = t >> 2, cc = (t & 3) * 16;
    for (int k0 = 0; k0 < 1024; k0 += 64) {
      __syncthreads();
      *(uint4*)&As[0][r][cc]     = *(const uint4*)(A + (long)(m0 + r) * 1024 + k0 + cc);
      *(uint4*)&As[0][r][cc + 8] = *(const uint4*)(A + (long)(m0 + r) * 1024 + k0 + cc + 8);
#pragma unroll
      for (int ee = 0; ee < 16; ++ee) {
        Bs[0][0][r][cc + ee] = f2b(Bf[(long)(n0 + r) * 1024 + k0 + cc + ee]);
        Bs[0][1][r][cc + ee] = f2b(Bf[(long)(n0 + 64 + r) * 1024 + k0 + cc + ee]);
      }
      __syncthreads();
#pragma unroll
      for (int kk = 0; kk < 2; ++kk) {
        bf16x8 bfx[2];
        const int rowB = (w << 4) + lr;
#pragma unroll
        for (int e = 0; e < 2; ++e)
          bfx[e] = *(const bf16x8*)&Bs[0][e][rowB][kk * 32 + lq * 8];
#pragma unroll
        for (int mt = 0; mt < 4; ++mt) {
          bf16x8 af = *(const bf16x8*)&As[0][(mt << 4) + lr][kk * 32 + lq * 8];
#pragma unroll
          for (int e = 0; e < 2; ++e)
            acc[e][mt] = __builtin_amdgcn_mfma_f32_16x16x32_bf16(af, bfx[e], acc[e][mt], 0, 0, 0);
        }
      }
    }
  }
#pragma unroll
  for (int e = 0; e < 2; ++e) {
    const int col = n0 + e * 64 + (w << 4) + lr;
    if (mode == 0) {
      u16* C = (u16*)Cv;
#pragma unroll
      for (int mt = 0; mt < 4; ++mt)
#pragma unroll
        for (int i = 0; i < 4; ++i)
          C[(m0 + mt * 16 + lq * 4 + i) * 1024 + col] = f2b(acc[e][mt][i]);
    } else {
      float* C = (float*)Cv;
#pragma unroll
      for (int mt = 0; mt < 4; ++mt)
#pragma unroll
        for (int i = 0; i < 4; ++i)
          C[(m0 + mt * 16 + lq * 4 + i) * 1024 + col] = acc[e][mt][i];
    }
  }
}

// ---------------------------------------------------------------------------
extern "C" void kernel_launch(void* const* d_in, const int* in_sizes, int n_in,
                              void* d_out, int out_size, void* d_ws, size_t ws_size,
                              hipStream_t stream) {
  const void* x    = d_in[0];   // (4096,1024)
  const void* wqkv = d_in[1];   // (3072,1024)
  const void* wout = d_in[2];   // (1024,1024)

  // ws layout: [reserved 256B][q 8.39MB][k 8.39MB][v^T 8.39MB][ao]
  u16* qb = (u16*)((char*)d_ws + 256);
  u16* kb = qb + 4194304;
  u16* vb = kb + 4194304;
  u16* ao = vb + 4194304;

  k_qkv_rope<<<dim3(16, 32), 256, 0, stream>>>(x, wqkv, qb, kb, vb);
  k_attn    <<<dim3(16, 32), 256, 0, stream>>>(qb, kb, vb, ao);
  k_gemm_out<<<dim3(8, 64), 256, 0, stream>>>(ao, wout, d_out);
}